// Round 3
// baseline (233.192 us; speedup 1.0000x reference)
//
#include <hip/hip_runtime.h>

// YOLO loss forward on MI355X.
// input/target: (B=256, C=25, S=64, S=64) fp32, row-major.
// Memory-bound reduction: 209.7 MB -> 1 float. Roofline ~33 us at 6.3 TB/s.
//
// V4: copy-shaped streaming. V1-V3 all plateaued at 83 us / 2.5 TB/s
// delivered regardless of occupancy (34-67%) -> limiter is the per-wave
// instruction stream shape: branchy consume code prevented the compiler
// from pipelining loads (VGPR stayed 32-40, ~1-2 loads in flight).
// Changes:
//  - split class / box into separate kernels (separate rocprof rows = ablation)
//  - class kernel is branchless and copy-shaped: 3 coalesced streams,
//    consume is pure FMA; mask precomputed as float4 (4 MB, L2-resident).
//  - box kernel: V1 box math, branch-light, own launch.

#define COORD 5.0f
#define NOOBJ 0.5f

constexpr int B = 256;
constexpr int C = 25;
constexpr int S = 64;
constexpr int SS = S * S;                    // 4096 spatial positions per image
constexpr int CH_STRIDE4 = SS / 4;           // 1024 float4 per channel plane
constexpr int IMG_STRIDE4 = C * CH_STRIDE4;  // 25600 float4 per image
constexpr int N4 = B * SS / 4;               // 262144 float4-groups (= 2^18)

constexpr int THREADS = 256;
constexpr int CLASS_CH = 20;                              // channels 5..24
constexpr int CLASS_ITEMS = CLASS_CH * N4;                // 5,242,880
constexpr int CLASS_BLOCKS = 2048;
constexpr int CLASS_THREADS_TOT = CLASS_BLOCKS * THREADS; // 524,288
constexpr int CLASS_IPT = CLASS_ITEMS / CLASS_THREADS_TOT; // 10 items/thread
constexpr int BOX_BLOCKS = N4 / THREADS;                  // 1024
constexpr int MASK_BYTES = N4 * 16;                       // float4 per group, 4 MB

__device__ __forceinline__ float comp(const float4 v, int k) {
    switch (k) {
        case 0: return v.x;
        case 1: return v.y;
        case 2: return v.z;
        default: return v.w;
    }
}

__device__ __forceinline__ void block_reduce_atomic(float acc, float* out) {
    #pragma unroll
    for (int off = 32; off > 0; off >>= 1)
        acc += __shfl_down(acc, off, 64);
    __shared__ float smem[4];
    const int lane = threadIdx.x & 63;
    const int wid = threadIdx.x >> 6;
    if (lane == 0) smem[wid] = acc;
    __syncthreads();
    if (threadIdx.x == 0) {
        atomicAdd(out, smem[0] + smem[1] + smem[2] + smem[3]);
    }
}

__global__ void zero_out_kernel(float* out) { out[0] = 0.0f; }

// float4 objectness mask per float4-group: mask[g] = (t4 > 0) ? 1.0 : 0.0
__global__ __launch_bounds__(256) void mask_kernel(
        const float4* __restrict__ tg, float4* __restrict__ mask) {
    const int g = blockIdx.x * 256 + threadIdx.x;  // grid = N4/256 blocks
    const float4 t4 = tg[(g >> 10) * IMG_STRIDE4 + (g & 1023) + 4 * CH_STRIDE4];
    mask[g] = make_float4(t4.x > 0.0f ? 1.0f : 0.0f,
                          t4.y > 0.0f ? 1.0f : 0.0f,
                          t4.z > 0.0f ? 1.0f : 0.0f,
                          t4.w > 0.0f ? 1.0f : 0.0f);
}

// ---- class terms: sum m * (p_c - t_c)^2 over channels 5..24 ----
// Copy-shaped: branchless straight-line body, 3 coalesced streams.
__global__ __launch_bounds__(256) void class_kernel(
        const float4* __restrict__ in, const float4* __restrict__ tg,
        const float4* __restrict__ mask,  // may be null -> derive from tg
        float* __restrict__ out) {
    const int t = blockIdx.x * THREADS + threadIdx.x;
    float acc = 0.0f;

    #pragma unroll
    for (int i = 0; i < CLASS_IPT; i += 2) {
        const int f0 = t + (i + 0) * CLASS_THREADS_TOT;
        const int f1 = t + (i + 1) * CLASS_THREADS_TOT;
        const int c0 = 5 + (f0 >> 18);        // N4 = 2^18
        const int c1 = 5 + (f1 >> 18);
        const int g0 = f0 & (N4 - 1);
        const int g1 = f1 & (N4 - 1);
        const int b0 = (g0 >> 10) * IMG_STRIDE4 + (g0 & 1023);
        const int b1 = (g1 >> 10) * IMG_STRIDE4 + (g1 & 1023);

        const float4 pv0 = in[b0 + c0 * CH_STRIDE4];
        const float4 tv0 = tg[b0 + c0 * CH_STRIDE4];
        const float4 pv1 = in[b1 + c1 * CH_STRIDE4];
        const float4 tv1 = tg[b1 + c1 * CH_STRIDE4];
        float4 m0, m1;
        if (mask) {
            m0 = mask[g0];
            m1 = mask[g1];
        } else {
            const float4 a = tg[b0 + 4 * CH_STRIDE4];
            const float4 b = tg[b1 + 4 * CH_STRIDE4];
            m0 = make_float4(a.x > 0.0f ? 1.0f : 0.0f, a.y > 0.0f ? 1.0f : 0.0f,
                             a.z > 0.0f ? 1.0f : 0.0f, a.w > 0.0f ? 1.0f : 0.0f);
            m1 = make_float4(b.x > 0.0f ? 1.0f : 0.0f, b.y > 0.0f ? 1.0f : 0.0f,
                             b.z > 0.0f ? 1.0f : 0.0f, b.w > 0.0f ? 1.0f : 0.0f);
        }

        float d;
        d = pv0.x - tv0.x; acc = fmaf(m0.x * d, d, acc);
        d = pv0.y - tv0.y; acc = fmaf(m0.y * d, d, acc);
        d = pv0.z - tv0.z; acc = fmaf(m0.z * d, d, acc);
        d = pv0.w - tv0.w; acc = fmaf(m0.w * d, d, acc);
        d = pv1.x - tv1.x; acc = fmaf(m1.x * d, d, acc);
        d = pv1.y - tv1.y; acc = fmaf(m1.y * d, d, acc);
        d = pv1.z - tv1.z; acc = fmaf(m1.z * d, d, acc);
        d = pv1.w - tv1.w; acc = fmaf(m1.w * d, d, acc);
    }

    block_reduce_atomic(acc, out);
}

// ---- box terms: channels 0..4 (coord + iou + conf + noobj) ----
__global__ __launch_bounds__(256) void box_kernel(
        const float4* __restrict__ in, const float4* __restrict__ tg,
        float* __restrict__ out) {
    const int g = blockIdx.x * THREADS + threadIdx.x;  // < N4
    const int base = (g >> 10) * IMG_STRIDE4 + (g & 1023);

    const float4 p0 = in[base + 0 * CH_STRIDE4];
    const float4 p1 = in[base + 1 * CH_STRIDE4];
    const float4 p2 = in[base + 2 * CH_STRIDE4];
    const float4 p3 = in[base + 3 * CH_STRIDE4];
    const float4 p4 = in[base + 4 * CH_STRIDE4];
    const float4 t0 = tg[base + 0 * CH_STRIDE4];
    const float4 t1 = tg[base + 1 * CH_STRIDE4];
    const float4 t2 = tg[base + 2 * CH_STRIDE4];
    const float4 t3 = tg[base + 3 * CH_STRIDE4];
    const float4 t4 = tg[base + 4 * CH_STRIDE4];

    float acc = 0.0f;
    const float invBlocks = 1.0f / (float)S;
    #pragma unroll
    for (int k = 0; k < 4; ++k) {
        const float px = comp(p0, k), py = comp(p1, k);
        const float pw = comp(p2, k), ph = comp(p3, k);
        const float pc = comp(p4, k);
        const float tx = comp(t0, k), ty = comp(t1, k);
        const float tw = comp(t2, k), th = comp(t3, k);
        const float tc = comp(t4, k);
        const float m = (tc > 0.0f) ? 1.0f : 0.0f;

        // IoU (forward values only)
        const float c1x = px * invBlocks, c1y = py * invBlocks;
        const float c2x = tx * invBlocks, c2y = ty * invBlocks;
        const float x1a = c1x - pw * 0.5f, x2a = c1x + pw * 0.5f;
        const float y1a = c1y - ph * 0.5f, y2a = c1y + ph * 0.5f;
        const float x1b = c2x - tw * 0.5f, x2b = c2x + tw * 0.5f;
        const float y1b = c2y - th * 0.5f, y2b = c2y + th * 0.5f;
        const float dx = fminf(x2a, x2b) - fmaxf(x1a, x1b);
        const float dy = fminf(y2a, y2b) - fmaxf(y1a, y1b);
        const float inter = dx * dy;
        const float uni = pw * ph + tw * th - inter;
        const bool pos = (dx > 0.0f) && (dy > 0.0f);
        const float iou = pos ? (inter / uni) : 0.0f;

        // coord terms
        const float ex = px - tx, ey = py - ty;
        acc += COORD * m * (ex * ex + ey * ey);
        const float sw = sqrtf(pw) - sqrtf(tw);
        const float sh = sqrtf(ph) - sqrtf(th);
        acc += COORD * m * (sw * sw + sh * sh);
        // confidence terms
        const float ec = pc - iou;
        acc += m * ec * ec;
        acc += NOOBJ * (1.0f - m) * (pc * pc);
    }

    block_reduce_atomic(acc, out);
}

extern "C" void kernel_launch(void* const* d_in, const int* in_sizes, int n_in,
                              void* d_out, int out_size, void* d_ws, size_t ws_size,
                              hipStream_t stream) {
    const float4* in = (const float4*)d_in[0];
    const float4* tg = (const float4*)d_in[1];
    float* out = (float*)d_out;

    // d_out is re-poisoned to 0xAA before every timed launch -> zero it first.
    zero_out_kernel<<<1, 1, 0, stream>>>(out);

    float4* mask = nullptr;
    if (d_ws != nullptr && ws_size >= (size_t)MASK_BYTES) {
        mask = (float4*)d_ws;
        mask_kernel<<<N4 / 256, 256, 0, stream>>>(tg, mask);
    }

    class_kernel<<<CLASS_BLOCKS, THREADS, 0, stream>>>(in, tg, mask, out);
    box_kernel<<<BOX_BLOCKS, THREADS, 0, stream>>>(in, tg, out);
}

// Round 4
// 228.203 us; speedup vs baseline: 1.0219x; 1.0219x over previous
//
#include <hip/hip_runtime.h>

// YOLO loss forward on MI355X.
// input/target: (B=256, C=25, S=64, S=64) fp32, row-major.
// Memory-bound reduction: 209.7 MB -> 1 float.
//
// V5: stop wasting delivered bandwidth. V4 ablation showed class_kernel
// delivers 3.87 TB/s to the CUs but 80 MB of that was the 4 MB mask plane
// re-read 20x (L2-hit, but L2 hits consume the same per-CU return path).
// Restructure: one thread owns 5 class channels of one float4-group:
//   1 x t4 load (mask computed inline, branchless) + 10 value loads,
//   all 11 independent and issued before any consume.
// t4 plane re-read only 4x (16.8 MB); the 4 blocks sharing a t4 chunk are
// 1024 apart in blockIdx == same XCD under default %8 round-robin -> L2-hot.
// Box part merged into the same grid (blocks after class blocks).
// No mask workspace, no mask kernel.

#define COORD 5.0f
#define NOOBJ 0.5f

constexpr int B = 256;
constexpr int C = 25;
constexpr int S = 64;
constexpr int SS = S * S;                    // 4096 spatial positions per image
constexpr int CH_STRIDE4 = SS / 4;           // 1024 float4 per channel plane
constexpr int IMG_STRIDE4 = C * CH_STRIDE4;  // 25600 float4 per image
constexpr int N4 = B * SS / 4;               // 262144 float4-groups (= 2^18)

constexpr int THREADS = 256;
constexpr int CSETS = 4;                     // 4 channel-sets x 5 channels = 20
constexpr int CLASS_BLOCKS = CSETS * N4 / THREADS;   // 4096
constexpr int BOX_BLOCKS = N4 / THREADS;             // 1024
constexpr int TOTAL_BLOCKS = CLASS_BLOCKS + BOX_BLOCKS; // 5120

__device__ __forceinline__ float comp(const float4 v, int k) {
    switch (k) {
        case 0: return v.x;
        case 1: return v.y;
        case 2: return v.z;
        default: return v.w;
    }
}

__device__ __forceinline__ void block_reduce_atomic(float acc, float* out) {
    #pragma unroll
    for (int off = 32; off > 0; off >>= 1)
        acc += __shfl_down(acc, off, 64);
    __shared__ float smem[4];
    const int lane = threadIdx.x & 63;
    const int wid = threadIdx.x >> 6;
    if (lane == 0) smem[wid] = acc;
    __syncthreads();
    if (threadIdx.x == 0) {
        atomicAdd(out, smem[0] + smem[1] + smem[2] + smem[3]);
    }
}

__global__ void zero_out_kernel(float* out) { out[0] = 0.0f; }

__global__ __launch_bounds__(256, 4) void yolo_loss_kernel(
        const float4* __restrict__ in, const float4* __restrict__ tg,
        float* __restrict__ out) {
    float acc = 0.0f;

    if (blockIdx.x < CLASS_BLOCKS) {
        // ---- class terms: 5 channels of one group per thread ----
        const int t = blockIdx.x * THREADS + threadIdx.x;   // < 4*N4 = 2^20
        const int cset = t >> 18;                           // 0..3
        const int g = t & (N4 - 1);
        const int base = (g >> 10) * IMG_STRIDE4 + (g & 1023);
        const int cbase = base + (5 + cset * 5) * CH_STRIDE4;

        // 11 independent loads, issued before any consumption.
        const float4 t4  = tg[base + 4 * CH_STRIDE4];
        const float4 pv0 = in[cbase + 0 * CH_STRIDE4];
        const float4 tv0 = tg[cbase + 0 * CH_STRIDE4];
        const float4 pv1 = in[cbase + 1 * CH_STRIDE4];
        const float4 tv1 = tg[cbase + 1 * CH_STRIDE4];
        const float4 pv2 = in[cbase + 2 * CH_STRIDE4];
        const float4 tv2 = tg[cbase + 2 * CH_STRIDE4];
        const float4 pv3 = in[cbase + 3 * CH_STRIDE4];
        const float4 tv3 = tg[cbase + 3 * CH_STRIDE4];
        const float4 pv4 = in[cbase + 4 * CH_STRIDE4];
        const float4 tv4 = tg[cbase + 4 * CH_STRIDE4];

        // branchless mask (v_cmp + v_cndmask)
        const float mx = t4.x > 0.0f ? 1.0f : 0.0f;
        const float my = t4.y > 0.0f ? 1.0f : 0.0f;
        const float mz = t4.z > 0.0f ? 1.0f : 0.0f;
        const float mw = t4.w > 0.0f ? 1.0f : 0.0f;

        float d;
        d = pv0.x - tv0.x; acc = fmaf(mx * d, d, acc);
        d = pv0.y - tv0.y; acc = fmaf(my * d, d, acc);
        d = pv0.z - tv0.z; acc = fmaf(mz * d, d, acc);
        d = pv0.w - tv0.w; acc = fmaf(mw * d, d, acc);
        d = pv1.x - tv1.x; acc = fmaf(mx * d, d, acc);
        d = pv1.y - tv1.y; acc = fmaf(my * d, d, acc);
        d = pv1.z - tv1.z; acc = fmaf(mz * d, d, acc);
        d = pv1.w - tv1.w; acc = fmaf(mw * d, d, acc);
        d = pv2.x - tv2.x; acc = fmaf(mx * d, d, acc);
        d = pv2.y - tv2.y; acc = fmaf(my * d, d, acc);
        d = pv2.z - tv2.z; acc = fmaf(mz * d, d, acc);
        d = pv2.w - tv2.w; acc = fmaf(mw * d, d, acc);
        d = pv3.x - tv3.x; acc = fmaf(mx * d, d, acc);
        d = pv3.y - tv3.y; acc = fmaf(my * d, d, acc);
        d = pv3.z - tv3.z; acc = fmaf(mz * d, d, acc);
        d = pv3.w - tv3.w; acc = fmaf(mw * d, d, acc);
        d = pv4.x - tv4.x; acc = fmaf(mx * d, d, acc);
        d = pv4.y - tv4.y; acc = fmaf(my * d, d, acc);
        d = pv4.z - tv4.z; acc = fmaf(mz * d, d, acc);
        d = pv4.w - tv4.w; acc = fmaf(mw * d, d, acc);
    } else {
        // ---- box terms: channels 0..4 (coord + iou + conf + noobj) ----
        const int g = (blockIdx.x - CLASS_BLOCKS) * THREADS + threadIdx.x; // < N4
        const int base = (g >> 10) * IMG_STRIDE4 + (g & 1023);

        const float4 p0 = in[base + 0 * CH_STRIDE4];
        const float4 p1 = in[base + 1 * CH_STRIDE4];
        const float4 p2 = in[base + 2 * CH_STRIDE4];
        const float4 p3 = in[base + 3 * CH_STRIDE4];
        const float4 p4 = in[base + 4 * CH_STRIDE4];
        const float4 t0 = tg[base + 0 * CH_STRIDE4];
        const float4 t1 = tg[base + 1 * CH_STRIDE4];
        const float4 t2 = tg[base + 2 * CH_STRIDE4];
        const float4 t3 = tg[base + 3 * CH_STRIDE4];
        const float4 t4 = tg[base + 4 * CH_STRIDE4];

        const float invBlocks = 1.0f / (float)S;
        #pragma unroll
        for (int k = 0; k < 4; ++k) {
            const float px = comp(p0, k), py = comp(p1, k);
            const float pw = comp(p2, k), ph = comp(p3, k);
            const float pc = comp(p4, k);
            const float tx = comp(t0, k), ty = comp(t1, k);
            const float tw = comp(t2, k), th = comp(t3, k);
            const float tc = comp(t4, k);
            const float m = (tc > 0.0f) ? 1.0f : 0.0f;

            // IoU (forward values only)
            const float c1x = px * invBlocks, c1y = py * invBlocks;
            const float c2x = tx * invBlocks, c2y = ty * invBlocks;
            const float x1a = c1x - pw * 0.5f, x2a = c1x + pw * 0.5f;
            const float y1a = c1y - ph * 0.5f, y2a = c1y + ph * 0.5f;
            const float x1b = c2x - tw * 0.5f, x2b = c2x + tw * 0.5f;
            const float y1b = c2y - th * 0.5f, y2b = c2y + th * 0.5f;
            const float dx = fminf(x2a, x2b) - fmaxf(x1a, x1b);
            const float dy = fminf(y2a, y2b) - fmaxf(y1a, y1b);
            const float inter = dx * dy;
            const float uni = pw * ph + tw * th - inter;
            const bool pos = (dx > 0.0f) && (dy > 0.0f);
            const float iou = pos ? (inter / uni) : 0.0f;

            // coord terms
            const float ex = px - tx, ey = py - ty;
            acc += COORD * m * (ex * ex + ey * ey);
            const float sw = sqrtf(pw) - sqrtf(tw);
            const float sh = sqrtf(ph) - sqrtf(th);
            acc += COORD * m * (sw * sw + sh * sh);
            // confidence terms
            const float ec = pc - iou;
            acc += m * ec * ec;
            acc += NOOBJ * (1.0f - m) * (pc * pc);
        }
    }

    block_reduce_atomic(acc, out);
}

extern "C" void kernel_launch(void* const* d_in, const int* in_sizes, int n_in,
                              void* d_out, int out_size, void* d_ws, size_t ws_size,
                              hipStream_t stream) {
    const float4* in = (const float4*)d_in[0];
    const float4* tg = (const float4*)d_in[1];
    float* out = (float*)d_out;

    // d_out is re-poisoned to 0xAA before every timed launch -> zero it first.
    zero_out_kernel<<<1, 1, 0, stream>>>(out);

    yolo_loss_kernel<<<TOTAL_BLOCKS, THREADS, 0, stream>>>(in, tg, out);
}